// Round 2
// baseline (1321.617 us; speedup 1.0000x reference)
//
#include <hip/hip_runtime.h>
#include <stdint.h>

#define EPS 1e-5f
#define NPB 2048   // scan items per block

typedef __attribute__((ext_vector_type(8))) __bf16 bf16x8;
typedef __attribute__((ext_vector_type(8))) unsigned short ushort8;
typedef __attribute__((ext_vector_type(4))) float f32x4;
typedef __attribute__((ext_vector_type(4))) int i32x4;

__device__ __forceinline__ unsigned short f2bf(float f) {
    union { float f; unsigned u; } c; c.f = f;
    unsigned r = c.u + 0x7fffu + ((c.u >> 16) & 1u);   // RNE truncate to bf16
    return (unsigned short)(r >> 16);
}

// ---- pass 1: per-channel sum/sumsq (+ optional out_index histogram) -----
__global__ void stats_hist_kernel(const float* __restrict__ f, const int* __restrict__ out_idx,
                                  float* __restrict__ wsf, int* __restrict__ cnt,
                                  int n, int do_hist) {
    __shared__ float s_sum[32];
    __shared__ float s_sq[32];
    int tid = threadIdx.x;
    if (tid < 32) { s_sum[tid] = 0.f; s_sq[tid] = 0.f; }
    __syncthreads();
    int c = tid & 31;
    int g = tid >> 5;
    float sum = 0.f, sq = 0.f;
    for (int r = blockIdx.x * 8 + g; r < n; r += gridDim.x * 8) {
        float v = f[(size_t)r * 32 + c];
        sum += v; sq += v * v;
        if (do_hist && c == 0) atomicAdd(&cnt[out_idx[r]], 1);
    }
    atomicAdd(&s_sum[c], sum);
    atomicAdd(&s_sq[c], sq);
    __syncthreads();
    if (tid < 32) {
        atomicAdd(&wsf[tid],      s_sum[tid]);
        atomicAdd(&wsf[32 + tid], s_sq[tid]);
    }
}

// ---- fold BN into per-channel scale/shift -------------------------------
__global__ void finalize_kernel(const float* __restrict__ gamma, const float* __restrict__ beta,
                                float* __restrict__ wsf, int n) {
    int c = threadIdx.x;
    if (c < 32) {
        float inv_n = 1.f / (float)n;
        float mean = wsf[c] * inv_n;
        float var  = wsf[32 + c] * inv_n - mean * mean;
        float scale = gamma[c] * rsqrtf(var + EPS);
        wsf[64 + c] = scale;
        wsf[96 + c] = beta[c] - mean * scale;
    }
}

// ---- scan step 1: per-block exclusive scan of cnt -> offs, block totals -
__global__ void scan1_kernel(const int* __restrict__ cnt, int* __restrict__ offs,
                             int* __restrict__ partials, int n) {
    __shared__ int s[256];
    int tid = threadIdx.x;
    int base = blockIdx.x * NPB + tid * 8;
    int v[8];
    if (base + 8 <= n) {
        i32x4 a = *(const i32x4*)(cnt + base);
        i32x4 b = *(const i32x4*)(cnt + base + 4);
        #pragma unroll
        for (int i = 0; i < 4; ++i) { v[i] = a[i]; v[4 + i] = b[i]; }
    } else {
        #pragma unroll
        for (int i = 0; i < 8; ++i) v[i] = (base + i < n) ? cnt[base + i] : 0;
    }
    int sum = 0;
    #pragma unroll
    for (int i = 0; i < 8; ++i) sum += v[i];
    s[tid] = sum; __syncthreads();
    for (int d = 1; d < 256; d <<= 1) {
        int t = (tid >= d) ? s[tid - d] : 0;
        __syncthreads();
        s[tid] += t;
        __syncthreads();
    }
    int run = s[tid] - sum;   // exclusive base for this thread
    #pragma unroll
    for (int i = 0; i < 8; ++i) {
        if (base + i < n) offs[base + i] = run;
        run += v[i];
    }
    if (tid == 0) partials[blockIdx.x] = s[255];
}

// ---- scan step 2: exclusive scan of block totals (single block) ---------
__global__ void scan2_kernel(int* __restrict__ partials, int nparts) {
    __shared__ int s[1024];
    int tid = threadIdx.x;
    int v = (tid < nparts) ? partials[tid] : 0;
    s[tid] = v; __syncthreads();
    for (int d = 1; d < 1024; d <<= 1) {
        int t = (tid >= d) ? s[tid - d] : 0;
        __syncthreads();
        s[tid] += t;
        __syncthreads();
    }
    if (tid < nparts) partials[tid] = s[tid] - v;
}

// ---- scan step 3: add scanned block bases back --------------------------
__global__ void scan3_kernel(int* __restrict__ offs, const int* __restrict__ partials, int n) {
    int tid = threadIdx.x;
    int add = partials[blockIdx.x];
    int base = blockIdx.x * NPB + tid * 8;
    if (base + 8 <= n) {
        i32x4 a = *(i32x4*)(offs + base);
        i32x4 b = *(i32x4*)(offs + base + 4);
        #pragma unroll
        for (int i = 0; i < 4; ++i) { a[i] += add; b[i] += add; }
        *(i32x4*)(offs + base) = a;
        *(i32x4*)(offs + base + 4) = b;
    } else {
        #pragma unroll
        for (int i = 0; i < 8; ++i) if (base + i < n) offs[base + i] += add;
    }
}

// ---- build order[]: point ids grouped by output (atomic bump on offs) ---
// After this kernel offs[o] == inclusive prefix (segment end).
__global__ void scatter_kernel(const int* __restrict__ out_idx, int* __restrict__ offs,
                               int* __restrict__ order, int n) {
    int p = blockIdx.x * blockDim.x + threadIdx.x;
    int stride = gridDim.x * blockDim.x;
    for (; p < n; p += stride) {
        int o = out_idx[p];
        int pos = atomicAdd(&offs[o], 1);
        order[pos] = p;
    }
}

// ---- gather: wave owns 16 outputs, streams their points via masked MFMA -
__global__ __launch_bounds__(256) void gather_kernel(
    const float* __restrict__ feat, const float* __restrict__ weight,
    const int* __restrict__ off_idx, const int* __restrict__ order,
    const int* __restrict__ offs, const float* __restrict__ wsf,
    float* __restrict__ out, int n)
{
    const int lane = threadIdx.x & 63;
    const int m    = lane & 15;
    const int quad = lane >> 4;
    const int wave   = blockIdx.x * (blockDim.x >> 6) + (threadIdx.x >> 6);
    const int nwaves = gridDim.x * (blockDim.x >> 6);

    float scl[8], sft[8];
    #pragma unroll
    for (int j = 0; j < 8; ++j) {
        int k = quad * 8 + j;
        scl[j] = wsf[64 + k];
        sft[j] = wsf[96 + k];
    }

    ushort8 wf[8][4];
    #pragma unroll
    for (int t = 0; t < 8; ++t) {
        #pragma unroll
        for (int cb = 0; cb < 4; ++cb) {
            ushort8 v;
            #pragma unroll
            for (int j = 0; j < 8; ++j) {
                int k = quad * 8 + j;
                v[j] = f2bf(weight[((size_t)t * 32 + k) * 64 + cb * 16 + m]);
            }
            wf[t][cb] = v;
        }
    }

    const ushort8 zz = {0, 0, 0, 0, 0, 0, 0, 0};
    const int ngroups = (n + 15) >> 4;

    for (int g = wave; g < ngroups; g += nwaves) {
        const int o_base = g << 4;
        const int o_m = o_base + m;
        int start = 0, end = 0;
        if (o_m < n) {
            end = offs[o_m];
            start = (o_m > 0) ? offs[o_m - 1] : 0;
        }
        const int len = end - start;
        int lmax = len;
        #pragma unroll
        for (int d = 1; d <= 8; d <<= 1)
            lmax = max(lmax, __shfl_xor(lmax, d));

        f32x4 acc[4];
        #pragma unroll
        for (int cb = 0; cb < 4; ++cb) acc[cb] = (f32x4){0.f, 0.f, 0.f, 0.f};

        int p_next = (len > 0) ? order[start] : 0;
        for (int r = 0; r < lmax; ++r) {
            const bool act = r < len;
            const int p = p_next;
            p_next = (r + 1 < len) ? order[start + r + 1] : 0;
            const int tap = act ? off_idx[p] : -1;

            f32x4 x0 = (f32x4){0.f, 0.f, 0.f, 0.f};
            f32x4 x1 = (f32x4){0.f, 0.f, 0.f, 0.f};
            if (act) {
                const f32x4* fp = (const f32x4*)(feat + (size_t)p * 32 + quad * 8);
                x0 = fp[0];
                x1 = fp[1];
            }
            ushort8 af;
            #pragma unroll
            for (int j = 0; j < 4; ++j)
                af[j] = f2bf(fmaxf(x0[j] * scl[j] + sft[j], 0.f));
            #pragma unroll
            for (int j = 0; j < 4; ++j)
                af[4 + j] = f2bf(fmaxf(x1[j] * scl[4 + j] + sft[4 + j], 0.f));

            #pragma unroll
            for (int t = 0; t < 8; ++t) {
                ushort8 am = (tap == t) ? af : zz;
                bf16x8 a = __builtin_bit_cast(bf16x8, am);
                #pragma unroll
                for (int cb = 0; cb < 4; ++cb) {
                    acc[cb] = __builtin_amdgcn_mfma_f32_16x16x32_bf16(
                        a, __builtin_bit_cast(bf16x8, wf[t][cb]), acc[cb], 0, 0, 0);
                }
            }
        }

        #pragma unroll
        for (int i = 0; i < 4; ++i) {
            int o = o_base + quad * 4 + i;
            if (o < n) {
                #pragma unroll
                for (int cb = 0; cb < 4; ++cb)
                    out[(size_t)o * 64 + cb * 16 + m] = acc[cb][i];
            }
        }
    }
}

// ======================= fallback path (R1 algorithm) ====================
__global__ void fill_zero_kernel(float* __restrict__ p, size_t n4) {
    size_t i = (size_t)blockIdx.x * blockDim.x + threadIdx.x;
    size_t stride = (size_t)gridDim.x * blockDim.x;
    f32x4 z = (f32x4){0.f, 0.f, 0.f, 0.f};
    for (; i < n4; i += stride) ((f32x4*)p)[i] = z;
}

__global__ __launch_bounds__(256) void spconv_kernel(
    const float* __restrict__ feat, const float* __restrict__ weight,
    const int* __restrict__ out_idx, const int* __restrict__ off_idx,
    const float* __restrict__ wsf, float* __restrict__ out, int n)
{
    const int lane = threadIdx.x & 63;
    const int m    = lane & 15;
    const int quad = lane >> 4;
    const int wave   = blockIdx.x * (blockDim.x >> 6) + (threadIdx.x >> 6);
    const int nwaves = gridDim.x * (blockDim.x >> 6);

    float scl[8], sft[8];
    #pragma unroll
    for (int j = 0; j < 8; ++j) {
        int k = quad * 8 + j;
        scl[j] = wsf[64 + k];
        sft[j] = wsf[96 + k];
    }
    ushort8 wf[8][4];
    #pragma unroll
    for (int t = 0; t < 8; ++t) {
        #pragma unroll
        for (int cb = 0; cb < 4; ++cb) {
            ushort8 v;
            #pragma unroll
            for (int j = 0; j < 8; ++j)
                v[j] = f2bf(weight[((size_t)t * 32 + quad * 8 + j) * 64 + cb * 16 + m]);
            wf[t][cb] = v;
        }
    }

    const ushort8 zz = {0, 0, 0, 0, 0, 0, 0, 0};
    const int ntiles = (n + 15) >> 4;
    for (int tile = wave; tile < ntiles; tile += nwaves) {
        const int p_base = tile << 4;
        const int p  = p_base + m;
        const int pc = p < n ? p : n - 1;
        const f32x4* fp = (const f32x4*)(feat + (size_t)pc * 32 + quad * 8);
        f32x4 x0 = fp[0];
        f32x4 x1 = fp[1];
        ushort8 af;
        #pragma unroll
        for (int j = 0; j < 4; ++j) af[j] = f2bf(fmaxf(x0[j] * scl[j] + sft[j], 0.f));
        #pragma unroll
        for (int j = 0; j < 4; ++j) af[4 + j] = f2bf(fmaxf(x1[j] * scl[4 + j] + sft[4 + j], 0.f));
        const int tap = (p < n) ? off_idx[p] : -1;
        f32x4 acc[4];
        #pragma unroll
        for (int cb = 0; cb < 4; ++cb) acc[cb] = (f32x4){0.f, 0.f, 0.f, 0.f};
        #pragma unroll
        for (int t = 0; t < 8; ++t) {
            ushort8 am = (tap == t) ? af : zz;
            bf16x8 a = __builtin_bit_cast(bf16x8, am);
            #pragma unroll
            for (int cb = 0; cb < 4; ++cb)
                acc[cb] = __builtin_amdgcn_mfma_f32_16x16x32_bf16(
                    a, __builtin_bit_cast(bf16x8, wf[t][cb]), acc[cb], 0, 0, 0);
        }
        #pragma unroll
        for (int i = 0; i < 4; ++i) {
            int pr = p_base + quad * 4 + i;
            if (pr < n) {
                int o = out_idx[pr];
                #pragma unroll
                for (int cb = 0; cb < 4; ++cb)
                    atomicAdd(out + (size_t)o * 64 + cb * 16 + m, acc[cb][i]);
            }
        }
    }
}

extern "C" void kernel_launch(void* const* d_in, const int* in_sizes, int n_in,
                              void* d_out, int out_size, void* d_ws, size_t ws_size,
                              hipStream_t stream) {
    const float* features  = (const float*)d_in[0];
    const float* gamma     = (const float*)d_in[1];
    const float* beta      = (const float*)d_in[2];
    const float* weight    = (const float*)d_in[3];
    const int*   out_index = (const int*)d_in[4];
    const int*   off_index = (const int*)d_in[5];
    float* out = (float*)d_out;
    const int n = in_sizes[0] / 32;

    const int nparts = (n + NPB - 1) / NPB;
    const int NPAD   = nparts * NPB;

    // ws layout: [0,1024B) float stats | cnt[NPAD] | offs[NPAD] | order[NPAD] | partials[1024]
    float* wsf      = (float*)d_ws;
    int*   cnt      = (int*)((char*)d_ws + 1024);
    int*   offs     = cnt + NPAD;
    int*   order    = offs + NPAD;
    int*   partials = order + NPAD;
    size_t needed   = 1024 + ((size_t)3 * NPAD + 1024) * sizeof(int);

    if (ws_size >= needed && nparts <= 1024) {
        // CSR gather path: no output memset, no output atomics
        hipMemsetAsync(d_ws, 0, 1024, stream);
        hipMemsetAsync(cnt, 0, (size_t)n * sizeof(int), stream);
        stats_hist_kernel<<<2048, 256, 0, stream>>>(features, out_index, wsf, cnt, n, 1);
        finalize_kernel<<<1, 64, 0, stream>>>(gamma, beta, wsf, n);
        scan1_kernel<<<nparts, 256, 0, stream>>>(cnt, offs, partials, n);
        scan2_kernel<<<1, 1024, 0, stream>>>(partials, nparts);
        scan3_kernel<<<nparts, 256, 0, stream>>>(offs, partials, n);
        scatter_kernel<<<2048, 256, 0, stream>>>(out_index, offs, order, n);
        gather_kernel<<<4096, 256, 0, stream>>>(features, weight, off_index, order,
                                                offs, wsf, out, n);
    } else {
        // fallback: R1 scatter-atomic path with fast custom zero-fill
        hipMemsetAsync(d_ws, 0, 1024, stream);
        fill_zero_kernel<<<2048, 256, 0, stream>>>(out, (size_t)out_size / 4);
        stats_hist_kernel<<<2048, 256, 0, stream>>>(features, out_index, wsf, nullptr, n, 0);
        finalize_kernel<<<1, 64, 0, stream>>>(gamma, beta, wsf, n);
        spconv_kernel<<<4096, 256, 0, stream>>>(features, weight, out_index, off_index,
                                                wsf, out, n);
    }
}